// Round 4
// baseline (208.615 us; speedup 1.0000x reference)
//
#include <hip/hip_runtime.h>
#include <hip/hip_bf16.h>
#include <math.h>

#define B_  8
#define C_  128
#define CH_ 64
#define LX_ 128
#define LY_ 1024

typedef __attribute__((ext_vector_type(8)))  _Float16 half8;
typedef __attribute__((ext_vector_type(8)))  unsigned short ushort8;
typedef __attribute__((ext_vector_type(16))) float f32x16;

// ---------------- K0: wdTh[kh][c] = (fp16) W_down[c][kh]  (8192 elems) ------------
__global__ __launch_bounds__(256) void k0_prep(const float* __restrict__ wd,
                                               _Float16* __restrict__ wdTh) {
    int u = blockIdx.x * 256 + threadIdx.x;
    int kh = u >> 7, c = u & 127;
    wdTh[u] = (_Float16)wd[c * CH_ + kh];
}

// ---------------- K1: att = x^T @ W + b -> fp16  (+ zero Hx/Hy) -------------------
__global__ __launch_bounds__(128) void k1_att(
    const float* __restrict__ x, const float* __restrict__ y,
    const float* __restrict__ Wd, const float* __restrict__ bd,
    const float* __restrict__ Wp, const float* __restrict__ bp,
    _Float16* __restrict__ datt, _Float16* __restrict__ patt,
    float2* __restrict__ zero_region)
{
    // Hx+Hy zero fold-in: 2304 blocks * 128 thr * float2 = 589824 floats (exact)
    zero_region[blockIdx.x * 128 + threadIdx.x] = (float2){0.f, 0.f};

    const int blk = blockIdx.x;
    const float* src; const float* W; const float* bias; _Float16* dst; int L;
    int b, l0;
    if (blk < 256) {
        int row0 = blk * 4; b = row0 >> 7; l0 = row0 & 127;
        src = x; W = Wd; bias = bd; dst = datt; L = LX_;
    } else {
        int row0 = (blk - 256) * 4; b = row0 >> 10; l0 = row0 & 1023;
        src = y; W = Wp; bias = bp; dst = patt; L = LY_;
    }
    __shared__ float col[4][128];
    const int t = threadIdx.x;
    {
        const float* sp = src + ((long)b * C_ + t) * L + l0;
        float4 v = *(const float4*)sp;
        col[0][t] = v.x; col[1][t] = v.y; col[2][t] = v.z; col[3][t] = v.w;
    }
    __syncthreads();
    float acc0 = bias[t], acc1 = acc0, acc2 = acc0, acc3 = acc0;
    #pragma unroll 8
    for (int c = 0; c < 128; ++c) {
        float w = W[c * 128 + t];
        float s0 = col[0][c], s1 = col[1][c], s2 = col[2][c], s3 = col[3][c];
        acc0 = fmaf(s0, w, acc0); acc1 = fmaf(s1, w, acc1);
        acc2 = fmaf(s2, w, acc2); acc3 = fmaf(s3, w, acc3);
    }
    _Float16* dp = dst + ((long)b * L + l0) * C_ + t;
    dp[0]      = (_Float16)acc0; dp[C_]     = (_Float16)acc1;
    dp[2 * C_] = (_Float16)acc2; dp[3 * C_] = (_Float16)acc3;
}

// ---------------- K2: 32x32x16 MFMA pair-GEMM, reductions in registers ------------
// block = (b, 32 lx, 32 ly), 4 waves; wave w owns lx rows [8w, 8w+8).
// A = s[ly][c] (M=ly full tile), B = Wdown[c][kh]. Hy: 32 regs, zero LDS in loop.
// Hx: lane-tree + 1 shfl + plain ds_write per lxr. All atomics deferred to epilogue.
__global__ __launch_bounds__(256, 3) void k2_main(
    const _Float16* __restrict__ datt, const _Float16* __restrict__ patt,
    const _Float16* __restrict__ wdTh, const float* __restrict__ bdown,
    float* __restrict__ Hx, float* __restrict__ Hy)
{
    const int b     = blockIdx.x >> 2;
    const int lxblk = blockIdx.x & 3;
    const int lyblk = blockIdx.y;
    const int t   = threadIdx.x;
    const int w   = t >> 6;
    const int l   = t & 63;
    const int h   = l >> 5;     // 0/1: k-group and kh-half select
    const int c32 = l & 31;     // ly for A/pv; kh-col for B/D

    __shared__ _Float16 dTh[32][136];
    __shared__ _Float16 pTh[32][136];
    __shared__ __align__(16) char ubuf[17408];          // wt | (protH, compW)
    _Float16 (*wt)[136] = (_Float16(*)[136])ubuf;       // [64][136] fp16
    float (*protH)[66]  = (float(*)[66])ubuf;           // [32][66] f32
    float (*compW)[66]  = (float(*)[66])(ubuf + 8448);  // [32][66] f32

    // ---- stage (straight fp16 copies) ----
    {
        const ushort8* dsrc = (const ushort8*)(datt + ((long)b * LX_ + lxblk * 32) * C_);
        const ushort8* psrc = (const ushort8*)(patt + ((long)b * LY_ + lyblk * 32) * C_);
        #pragma unroll
        for (int i = 0; i < 2; ++i) {
            int idx = t + i * 256;
            int r = idx >> 4, c = (idx & 15) * 8;
            *(ushort8*)&dTh[r][c] = dsrc[idx];
            *(ushort8*)&pTh[r][c] = psrc[idx];
        }
        #pragma unroll
        for (int i = 0; i < 4; ++i) {
            int idx = t + i * 256;
            int r = idx >> 4, c = (idx & 15) * 8;
            *(ushort8*)&wt[r][c] = ((const ushort8*)wdTh)[idx];
        }
    }
    __syncthreads();

    // ---- hoist B-fragments, p-fragments, bias (registers for whole block) ----
    half8 bf[8][2];
    half8 pv[8];
    #pragma unroll
    for (int kt = 0; kt < 8; ++kt) {
        bf[kt][0] = *(const half8*)&wt[c32][kt * 16 + h * 8];
        bf[kt][1] = *(const half8*)&wt[32 + c32][kt * 16 + h * 8];
        pv[kt]    = *(const half8*)&pTh[c32][kt * 16 + h * 8];
    }
    const float bdr0 = bdown[c32], bdr1 = bdown[32 + c32];
    __syncthreads();
    for (int u = t; u < 4224; u += 256) ((float*)ubuf)[u] = 0.f;   // protH+compW
    __syncthreads();

    // ---- main loop: 8 lxr, no LDS atomics, no per-iter shfl chains ----
    const half8 hz = {};
    float hy0[16], hy1[16];
    #pragma unroll
    for (int r = 0; r < 16; ++r) { hy0[r] = 0.f; hy1[r] = 0.f; }

    #pragma unroll
    for (int lxr = 0; lxr < 8; ++lxr) {
        const int lxi = w * 8 + lxr;
        f32x16 acc0, acc1;
        #pragma unroll
        for (int r = 0; r < 16; ++r) { acc0[r] = bdr0; acc1[r] = bdr1; }
        #pragma unroll
        for (int kt = 0; kt < 8; ++kt) {
            half8 dv = *(const half8*)&dTh[lxi][kt * 16 + h * 8];   // broadcast read
            half8 s  = __builtin_elementwise_max(dv + pv[kt], hz);  // pk_add+pk_max
            acc0 = __builtin_amdgcn_mfma_f32_32x32x16_f16(s, bf[kt][0], acc0, 0, 0, 0);
            acc1 = __builtin_amdgcn_mfma_f32_32x32x16_f16(s, bf[kt][1], acc1, 0, 0, 0);
        }
        // D: col(kh)=c32(+32nt), row(ly)=(r&3)+8*(r>>2)+4h
        float s0 = 0.f, s1 = 0.f;
        #pragma unroll
        for (int r = 0; r < 16; ++r) {
            float v0 = fmaxf(acc0[r], 0.f);
            float v1 = fmaxf(acc1[r], 0.f);
            hy0[r] += v0; hy1[r] += v1;
            s0 += v0; s1 += v1;
        }
        s0 += __shfl_xor(s0, 32);
        s1 += __shfl_xor(s1, 32);
        compW[lxi][h * 32 + c32] = h ? s1 : s0;   // exclusive owner: plain write
    }

    // ---- epilogue: combine Hy across waves (LDS atomics, once) ----
    #pragma unroll
    for (int r = 0; r < 16; ++r) {
        int ly = (r & 3) + 8 * (r >> 2) + 4 * h;
        atomicAdd(&protH[ly][c32],      hy0[r]);
        atomicAdd(&protH[ly][32 + c32], hy1[r]);
    }
    __syncthreads();
    for (int u = t; u < 2048; u += 256) {
        int r = u >> 6, c = u & 63;
        atomicAdd(&Hx[((long)(b * LX_) + lxblk * 32 + r) * 64 + c], compW[r][c]);
        atomicAdd(&Hy[((long)(b * LY_) + lyblk * 32 + r) * 64 + c], protH[r][c]);
    }
}

// ---------------- K3: (H*invN) @ W_up + b_up -> gate -> transpose -> out ----------
__global__ __launch_bounds__(256) void k3_gate(
    const float* __restrict__ Hx, const float* __restrict__ Hy,
    const float* __restrict__ wup, const float* __restrict__ bup,
    const float* __restrict__ x, const float* __restrict__ y,
    float* __restrict__ out)
{
    const int b  = blockIdx.z;
    const int c0 = blockIdx.y * 32;
    const float* H; const float* xin; float* outp; int L; float invN; int l0;
    if (blockIdx.x < 4) {
        H = Hx; xin = x; outp = out; L = LX_; invN = 1.f / 1024.f;
        l0 = blockIdx.x * 32;
    } else {
        H = Hy; xin = y; outp = out + (long)B_ * C_ * LX_; L = LY_; invN = 1.f / 128.f;
        l0 = (blockIdx.x - 4) * 32;
    }
    const int t = threadIdx.x;
    __shared__ float Ht[32][68];
    __shared__ float Wt[64][36];
    __shared__ float gg[32][36];
    for (int u = t; u < 32 * 64; u += 256)
        Ht[u >> 6][u & 63] = H[((long)b * L + l0 + (u >> 6)) * 64 + (u & 63)];
    for (int u = t; u < 64 * 32; u += 256)
        Wt[u >> 5][u & 31] = wup[(u >> 5) * C_ + c0 + (u & 31)];
    __syncthreads();

    const int l = t >> 3, cg = (t & 7) * 4;
    float a0 = 0.f, a1 = 0.f, a2 = 0.f, a3 = 0.f;
    #pragma unroll 8
    for (int k = 0; k < 64; ++k) {
        float hv = Ht[l][k];
        float4 wv = *(const float4*)&Wt[k][cg];
        a0 = fmaf(hv, wv.x, a0); a1 = fmaf(hv, wv.y, a1);
        a2 = fmaf(hv, wv.z, a2); a3 = fmaf(hv, wv.w, a3);
    }
    float av[4] = {a0, a1, a2, a3};
    #pragma unroll
    for (int i = 0; i < 4; ++i) {
        float v = fmaf(av[i], invN, bup[c0 + cg + i]);
        float sg = 1.f / (1.f + expf(-v));
        gg[l][cg + i] = sg * tanhf(v);
    }
    __syncthreads();
    for (int u = t; u < 1024; u += 256) {
        int c = u >> 5, li = u & 31;
        long idx = ((long)b * C_ + c0 + c) * L + l0 + li;
        outp[idx] = xin[idx] * (0.5f + gg[li][c]);
    }
}

extern "C" void kernel_launch(void* const* d_in, const int* in_sizes, int n_in,
                              void* d_out, int out_size, void* d_ws, size_t ws_size,
                              hipStream_t stream) {
    (void)in_sizes; (void)n_in; (void)out_size; (void)ws_size;
    const float* x     = (const float*)d_in[0];
    const float* y     = (const float*)d_in[1];
    const float* Wdrug = (const float*)d_in[2];
    const float* bdrug = (const float*)d_in[3];
    const float* Wprot = (const float*)d_in[4];
    const float* bprot = (const float*)d_in[5];
    const float* Wdown = (const float*)d_in[6];
    const float* bdown = (const float*)d_in[7];
    const float* Wup   = (const float*)d_in[8];
    const float* bup   = (const float*)d_in[9];
    float* out = (float*)d_out;
    char* ws = (char*)d_ws;

    _Float16* datt = (_Float16*)ws;                    // 131072 halves
    _Float16* patt = (_Float16*)(ws + 262144);         // 1048576 halves
    float*    Hx   = (float*)(ws + 2359296);           // 65536 f32
    float*    Hy   = (float*)(ws + 2621440);           // 524288 f32
    _Float16* wdTh = (_Float16*)(ws + 4718592);        // 8192 halves

    hipLaunchKernelGGL(k0_prep, dim3(32), dim3(256), 0, stream, Wdown, wdTh);
    hipLaunchKernelGGL(k1_att, dim3(2304), dim3(128), 0, stream,
                       x, y, Wdrug, bdrug, Wprot, bprot, datt, patt, (float2*)Hx);
    hipLaunchKernelGGL(k2_main, dim3(32, 32, 1), dim3(256), 0, stream,
                       datt, patt, wdTh, bdown, Hx, Hy);
    hipLaunchKernelGGL(k3_gate, dim3(36, 4, 8), dim3(256), 0, stream,
                       Hx, Hy, Wup, bup, x, y, out);
}

// Round 5
// 81.716 us; speedup vs baseline: 2.5529x; 2.5529x over previous
//
#include <hip/hip_runtime.h>
#include <hip/hip_bf16.h>
#include <math.h>

#define B_  8
#define C_  128
#define CH_ 64
#define LX_ 128
#define LY_ 1024

typedef __attribute__((ext_vector_type(8)))  _Float16 half8;
typedef __attribute__((ext_vector_type(8)))  unsigned short ushort8;
typedef __attribute__((ext_vector_type(16))) float f32x16;

// ---------------- K0: wdTh[kh][c] = (fp16) W_down[c][kh]  (8192 elems) ------------
__global__ __launch_bounds__(256) void k0_prep(const float* __restrict__ wd,
                                               _Float16* __restrict__ wdTh) {
    int u = blockIdx.x * 256 + threadIdx.x;
    int kh = u >> 7, c = u & 127;
    wdTh[u] = (_Float16)wd[c * CH_ + kh];
}

// ---------------- K1: att = x^T @ W + b -> fp16  (+ zero Hx/Hy) -------------------
__global__ __launch_bounds__(128) void k1_att(
    const float* __restrict__ x, const float* __restrict__ y,
    const float* __restrict__ Wd, const float* __restrict__ bd,
    const float* __restrict__ Wp, const float* __restrict__ bp,
    _Float16* __restrict__ datt, _Float16* __restrict__ patt,
    float2* __restrict__ zero_region)
{
    // Hx+Hy zero fold-in: 2304 blocks * 128 thr * float2 = 589824 floats (exact)
    zero_region[blockIdx.x * 128 + threadIdx.x] = (float2){0.f, 0.f};

    const int blk = blockIdx.x;
    const float* src; const float* W; const float* bias; _Float16* dst; int L;
    int b, l0;
    if (blk < 256) {
        int row0 = blk * 4; b = row0 >> 7; l0 = row0 & 127;
        src = x; W = Wd; bias = bd; dst = datt; L = LX_;
    } else {
        int row0 = (blk - 256) * 4; b = row0 >> 10; l0 = row0 & 1023;
        src = y; W = Wp; bias = bp; dst = patt; L = LY_;
    }
    __shared__ float col[4][128];
    const int t = threadIdx.x;
    {
        const float* sp = src + ((long)b * C_ + t) * L + l0;
        float4 v = *(const float4*)sp;
        col[0][t] = v.x; col[1][t] = v.y; col[2][t] = v.z; col[3][t] = v.w;
    }
    __syncthreads();
    float acc0 = bias[t], acc1 = acc0, acc2 = acc0, acc3 = acc0;
    #pragma unroll 8
    for (int c = 0; c < 128; ++c) {
        float w = W[c * 128 + t];
        float s0 = col[0][c], s1 = col[1][c], s2 = col[2][c], s3 = col[3][c];
        acc0 = fmaf(s0, w, acc0); acc1 = fmaf(s1, w, acc1);
        acc2 = fmaf(s2, w, acc2); acc3 = fmaf(s3, w, acc3);
    }
    _Float16* dp = dst + ((long)b * L + l0) * C_ + t;
    dp[0]      = (_Float16)acc0; dp[C_]     = (_Float16)acc1;
    dp[2 * C_] = (_Float16)acc2; dp[3 * C_] = (_Float16)acc3;
}

// ---------------- K2: 32x32x16 MFMA pair-GEMM, kh-split across waves --------------
// block = (b, 32 lx, 32 ly), 4 waves. Wave (wl=w&1, wk=w>>1): lx rows [16wl,16wl+16),
// kh cols [32wk, 32wk+32). Per wave: ONE f32x16 acc + bf[8] + pv[8] + hy[16]
// -> ~150 VGPR, fits (256,3) cap of 170 with no spill (R3's failure mode).
// Hy in regs across loop; Hx: intra-lane tree + 1 shfl + plain ds_write per iter.
__global__ __launch_bounds__(256, 3) void k2_main(
    const _Float16* __restrict__ datt, const _Float16* __restrict__ patt,
    const _Float16* __restrict__ wdTh, const float* __restrict__ bdown,
    float* __restrict__ Hx, float* __restrict__ Hy)
{
    const int b     = blockIdx.x >> 2;
    const int lxblk = blockIdx.x & 3;
    const int lyblk = blockIdx.y;
    const int t   = threadIdx.x;
    const int w   = t >> 6;
    const int wk  = w >> 1;     // kh half (0/1)
    const int wl  = w & 1;      // lx half (0/1)
    const int l   = t & 63;
    const int h   = l >> 5;     // k subgroup within MFMA operand
    const int c32 = l & 31;     // ly row for A/pv; kh col for B/D

    __shared__ _Float16 dTh[32][136];
    __shared__ _Float16 pTh[32][136];
    __shared__ __align__(16) char ubuf[17408];          // wt | (protH, compW)
    _Float16 (*wt)[136] = (_Float16(*)[136])ubuf;       // [64][136] fp16
    float (*protH)[66]  = (float(*)[66])ubuf;           // [32][66] f32
    float (*compW)[66]  = (float(*)[66])(ubuf + 8448);  // [32][66] f32

    // ---- stage (straight fp16 copies) ----
    {
        const ushort8* dsrc = (const ushort8*)(datt + ((long)b * LX_ + lxblk * 32) * C_);
        const ushort8* psrc = (const ushort8*)(patt + ((long)b * LY_ + lyblk * 32) * C_);
        #pragma unroll
        for (int i = 0; i < 2; ++i) {
            int idx = t + i * 256;
            int r = idx >> 4, c = (idx & 15) * 8;
            *(ushort8*)&dTh[r][c] = dsrc[idx];
            *(ushort8*)&pTh[r][c] = psrc[idx];
        }
        #pragma unroll
        for (int i = 0; i < 4; ++i) {
            int idx = t + i * 256;
            int r = idx >> 4, c = (idx & 15) * 8;
            *(ushort8*)&wt[r][c] = ((const ushort8*)wdTh)[idx];
        }
    }
    __syncthreads();

    // ---- hoist B-fragments (one kh-half), p-fragments, bias ----
    half8 bf[8];
    half8 pv[8];
    #pragma unroll
    for (int kt = 0; kt < 8; ++kt) {
        bf[kt] = *(const half8*)&wt[wk * 32 + c32][kt * 16 + h * 8];
        pv[kt] = *(const half8*)&pTh[c32][kt * 16 + h * 8];
    }
    const float bdr = bdown[wk * 32 + c32];
    __syncthreads();
    for (int u = t; u < 4224; u += 256) ((float*)ubuf)[u] = 0.f;   // protH+compW
    __syncthreads();

    // ---- main loop: 16 lxr per wave, no atomics, no runtime-indexed reg arrays ----
    const half8 hz = {};
    float hy[16];
    #pragma unroll
    for (int r = 0; r < 16; ++r) hy[r] = 0.f;

    #pragma unroll 1
    for (int lxr = 0; lxr < 16; ++lxr) {
        const int lxi = wl * 16 + lxr;
        f32x16 acc;
        #pragma unroll
        for (int r = 0; r < 16; ++r) acc[r] = bdr;
        #pragma unroll
        for (int kt = 0; kt < 8; ++kt) {
            half8 dv = *(const half8*)&dTh[lxi][kt * 16 + h * 8];   // broadcast read
            half8 s  = __builtin_elementwise_max(dv + pv[kt], hz);  // pk_add+pk_max
            acc = __builtin_amdgcn_mfma_f32_32x32x16_f16(s, bf[kt], acc, 0, 0, 0);
        }
        // D: col(kh)=wk*32+c32, row(ly)=(r&3)+8*(r>>2)+4h
        float s0 = 0.f;
        #pragma unroll
        for (int r = 0; r < 16; ++r) {
            float v = fmaxf(acc[r], 0.f);
            hy[r] += v;
            s0 += v;
        }
        s0 += __shfl_xor(s0, 32);             // add the other k-subgroup's rows
        if (h == 0) compW[lxi][wk * 32 + c32] = s0;   // exclusive owner: plain write
    }

    // ---- epilogue: combine Hy across wl-waves (LDS atomics, once) ----
    #pragma unroll
    for (int r = 0; r < 16; ++r) {
        int ly = (r & 3) + 8 * (r >> 2) + 4 * h;
        atomicAdd(&protH[ly][wk * 32 + c32], hy[r]);
    }
    __syncthreads();
    for (int u = t; u < 2048; u += 256) {
        int r = u >> 6, c = u & 63;
        atomicAdd(&Hx[((long)(b * LX_) + lxblk * 32 + r) * 64 + c], compW[r][c]);
        atomicAdd(&Hy[((long)(b * LY_) + lyblk * 32 + r) * 64 + c], protH[r][c]);
    }
}

// ---------------- K3: (H*invN) @ W_up + b_up -> gate -> transpose -> out ----------
__global__ __launch_bounds__(256) void k3_gate(
    const float* __restrict__ Hx, const float* __restrict__ Hy,
    const float* __restrict__ wup, const float* __restrict__ bup,
    const float* __restrict__ x, const float* __restrict__ y,
    float* __restrict__ out)
{
    const int b  = blockIdx.z;
    const int c0 = blockIdx.y * 32;
    const float* H; const float* xin; float* outp; int L; float invN; int l0;
    if (blockIdx.x < 4) {
        H = Hx; xin = x; outp = out; L = LX_; invN = 1.f / 1024.f;
        l0 = blockIdx.x * 32;
    } else {
        H = Hy; xin = y; outp = out + (long)B_ * C_ * LX_; L = LY_; invN = 1.f / 128.f;
        l0 = (blockIdx.x - 4) * 32;
    }
    const int t = threadIdx.x;
    __shared__ float Ht[32][68];
    __shared__ float Wt[64][36];
    __shared__ float gg[32][36];
    for (int u = t; u < 32 * 64; u += 256)
        Ht[u >> 6][u & 63] = H[((long)b * L + l0 + (u >> 6)) * 64 + (u & 63)];
    for (int u = t; u < 64 * 32; u += 256)
        Wt[u >> 5][u & 31] = wup[(u >> 5) * C_ + c0 + (u & 31)];
    __syncthreads();

    const int l = t >> 3, cg = (t & 7) * 4;
    float a0 = 0.f, a1 = 0.f, a2 = 0.f, a3 = 0.f;
    #pragma unroll 8
    for (int k = 0; k < 64; ++k) {
        float hv = Ht[l][k];
        float4 wv = *(const float4*)&Wt[k][cg];
        a0 = fmaf(hv, wv.x, a0); a1 = fmaf(hv, wv.y, a1);
        a2 = fmaf(hv, wv.z, a2); a3 = fmaf(hv, wv.w, a3);
    }
    float av[4] = {a0, a1, a2, a3};
    #pragma unroll
    for (int i = 0; i < 4; ++i) {
        float v = fmaf(av[i], invN, bup[c0 + cg + i]);
        float sg = 1.f / (1.f + expf(-v));
        gg[l][cg + i] = sg * tanhf(v);
    }
    __syncthreads();
    for (int u = t; u < 1024; u += 256) {
        int c = u >> 5, li = u & 31;
        long idx = ((long)b * C_ + c0 + c) * L + l0 + li;
        outp[idx] = xin[idx] * (0.5f + gg[li][c]);
    }
}

extern "C" void kernel_launch(void* const* d_in, const int* in_sizes, int n_in,
                              void* d_out, int out_size, void* d_ws, size_t ws_size,
                              hipStream_t stream) {
    (void)in_sizes; (void)n_in; (void)out_size; (void)ws_size;
    const float* x     = (const float*)d_in[0];
    const float* y     = (const float*)d_in[1];
    const float* Wdrug = (const float*)d_in[2];
    const float* bdrug = (const float*)d_in[3];
    const float* Wprot = (const float*)d_in[4];
    const float* bprot = (const float*)d_in[5];
    const float* Wdown = (const float*)d_in[6];
    const float* bdown = (const float*)d_in[7];
    const float* Wup   = (const float*)d_in[8];
    const float* bup   = (const float*)d_in[9];
    float* out = (float*)d_out;
    char* ws = (char*)d_ws;

    _Float16* datt = (_Float16*)ws;                    // 131072 halves
    _Float16* patt = (_Float16*)(ws + 262144);         // 1048576 halves
    float*    Hx   = (float*)(ws + 2359296);           // 65536 f32
    float*    Hy   = (float*)(ws + 2621440);           // 524288 f32
    _Float16* wdTh = (_Float16*)(ws + 4718592);        // 8192 halves

    hipLaunchKernelGGL(k0_prep, dim3(32), dim3(256), 0, stream, Wdown, wdTh);
    hipLaunchKernelGGL(k1_att, dim3(2304), dim3(128), 0, stream,
                       x, y, Wdrug, bdrug, Wprot, bprot, datt, patt, (float2*)Hx);
    hipLaunchKernelGGL(k2_main, dim3(32, 32, 1), dim3(256), 0, stream,
                       datt, patt, wdTh, bdown, Hx, Hy);
    hipLaunchKernelGGL(k3_gate, dim3(36, 4, 8), dim3(256), 0, stream,
                       Hx, Hy, Wup, bup, x, y, out);
}

// Round 6
// 80.405 us; speedup vs baseline: 2.5945x; 1.0163x over previous
//
#include <hip/hip_runtime.h>
#include <hip/hip_bf16.h>
#include <math.h>

#define B_  8
#define C_  128
#define CH_ 64
#define LX_ 128
#define LY_ 1024

typedef __attribute__((ext_vector_type(8)))  _Float16 half8;
typedef __attribute__((ext_vector_type(8)))  unsigned short ushort8;
typedef __attribute__((ext_vector_type(16))) float f32x16;

// ---------------- K1: att = x^T @ W + b -> fp16 ; blocks 0..63 also prep wdTh -----
__global__ __launch_bounds__(128) void k1_att(
    const float* __restrict__ x, const float* __restrict__ y,
    const float* __restrict__ Wd, const float* __restrict__ bd,
    const float* __restrict__ Wp, const float* __restrict__ bp,
    const float* __restrict__ Wdown,
    _Float16* __restrict__ datt, _Float16* __restrict__ patt,
    _Float16* __restrict__ wdTh)
{
    const int blk = blockIdx.x;
    const int t = threadIdx.x;
    if (blk < 64) {                        // wdTh[kh][c] = (fp16) W_down[c][kh]
        int u = blk * 128 + t;
        wdTh[u] = (_Float16)Wdown[(u & 127) * CH_ + (u >> 7)];
    }
    const float* src; const float* W; const float* bias; _Float16* dst; int L;
    int b, l0;
    if (blk < 256) {
        int row0 = blk * 4; b = row0 >> 7; l0 = row0 & 127;
        src = x; W = Wd; bias = bd; dst = datt; L = LX_;
    } else {
        int row0 = (blk - 256) * 4; b = row0 >> 10; l0 = row0 & 1023;
        src = y; W = Wp; bias = bp; dst = patt; L = LY_;
    }
    __shared__ float col[4][128];
    {
        const float* sp = src + ((long)b * C_ + t) * L + l0;
        float4 v = *(const float4*)sp;
        col[0][t] = v.x; col[1][t] = v.y; col[2][t] = v.z; col[3][t] = v.w;
    }
    __syncthreads();
    float acc0 = bias[t], acc1 = acc0, acc2 = acc0, acc3 = acc0;
    #pragma unroll 8
    for (int c = 0; c < 128; ++c) {
        float w = W[c * 128 + t];
        float s0 = col[0][c], s1 = col[1][c], s2 = col[2][c], s3 = col[3][c];
        acc0 = fmaf(s0, w, acc0); acc1 = fmaf(s1, w, acc1);
        acc2 = fmaf(s2, w, acc2); acc3 = fmaf(s3, w, acc3);
    }
    _Float16* dp = dst + ((long)b * L + l0) * C_ + t;
    dp[0]      = (_Float16)acc0; dp[C_]     = (_Float16)acc1;
    dp[2 * C_] = (_Float16)acc2; dp[3 * C_] = (_Float16)acc3;
}

// ---------------- K2: 32x32x16 MFMA pair-GEMM, dual chains, NO global atomics -----
// block = (b, 32 lx, 32 ly), 4 waves. Wave (wl=w&1, wk=w>>1): lx rows [16wl,16wl+16)
// processed in PAIRS (2 independent MFMA chains), kh cols [32wk, 32wk+32).
// Epilogue: plain coalesced stores of block partials to HxP/HyP slabs.
__global__ __launch_bounds__(256, 3) void k2_main(
    const _Float16* __restrict__ datt, const _Float16* __restrict__ patt,
    const _Float16* __restrict__ wdTh, const float* __restrict__ bdown,
    float* __restrict__ HxP, float* __restrict__ HyP)
{
    const int b     = blockIdx.x >> 2;
    const int lxblk = blockIdx.x & 3;
    const int lyblk = blockIdx.y;
    const int t   = threadIdx.x;
    const int w   = t >> 6;
    const int wk  = w >> 1;     // kh half (0/1)
    const int wl  = w & 1;      // lx half (0/1)
    const int l   = t & 63;
    const int h   = l >> 5;     // k subgroup within MFMA operand
    const int c32 = l & 31;     // ly row for A/pv; kh col for B/D

    __shared__ _Float16 dTh[32][136];
    __shared__ _Float16 pTh[32][136];
    __shared__ __align__(16) char ubuf[17408];          // wt | (protH, compW)
    _Float16 (*wt)[136] = (_Float16(*)[136])ubuf;       // [64][136] fp16
    float (*protH)[66]  = (float(*)[66])ubuf;           // [32][66] f32
    float (*compW)[66]  = (float(*)[66])(ubuf + 8448);  // [32][66] f32

    // ---- stage (straight fp16 copies) ----
    {
        const ushort8* dsrc = (const ushort8*)(datt + ((long)b * LX_ + lxblk * 32) * C_);
        const ushort8* psrc = (const ushort8*)(patt + ((long)b * LY_ + lyblk * 32) * C_);
        #pragma unroll
        for (int i = 0; i < 2; ++i) {
            int idx = t + i * 256;
            int r = idx >> 4, c = (idx & 15) * 8;
            *(ushort8*)&dTh[r][c] = dsrc[idx];
            *(ushort8*)&pTh[r][c] = psrc[idx];
        }
        #pragma unroll
        for (int i = 0; i < 4; ++i) {
            int idx = t + i * 256;
            int r = idx >> 4, c = (idx & 15) * 8;
            *(ushort8*)&wt[r][c] = ((const ushort8*)wdTh)[idx];
        }
    }
    __syncthreads();

    // ---- hoist B-fragments (one kh-half), p-fragments, bias vector ----
    half8 bf[8];
    half8 pv[8];
    #pragma unroll
    for (int kt = 0; kt < 8; ++kt) {
        bf[kt] = *(const half8*)&wt[wk * 32 + c32][kt * 16 + h * 8];
        pv[kt] = *(const half8*)&pTh[c32][kt * 16 + h * 8];
    }
    const float bdr = bdown[wk * 32 + c32];
    f32x16 biasv;
    #pragma unroll
    for (int r = 0; r < 16; ++r) biasv[r] = bdr;
    __syncthreads();
    for (int u = t; u < 4224; u += 256) ((float*)ubuf)[u] = 0.f;   // protH+compW
    __syncthreads();

    // ---- main loop: 8 row-pairs per wave, dual MFMA chains ----
    const half8 hz = {};
    float hy[16];
    #pragma unroll
    for (int r = 0; r < 16; ++r) hy[r] = 0.f;

    #pragma unroll 1
    for (int lxp = 0; lxp < 8; ++lxp) {
        const int lxa = wl * 16 + lxp * 2;
        const int lxb = lxa + 1;
        f32x16 aa, ab;
        {
            half8 dva = *(const half8*)&dTh[lxa][h * 8];
            half8 dvb = *(const half8*)&dTh[lxb][h * 8];
            half8 sa = __builtin_elementwise_max(dva + pv[0], hz);
            half8 sb = __builtin_elementwise_max(dvb + pv[0], hz);
            aa = __builtin_amdgcn_mfma_f32_32x32x16_f16(sa, bf[0], biasv, 0, 0, 0);
            ab = __builtin_amdgcn_mfma_f32_32x32x16_f16(sb, bf[0], biasv, 0, 0, 0);
        }
        #pragma unroll
        for (int kt = 1; kt < 8; ++kt) {
            half8 dva = *(const half8*)&dTh[lxa][kt * 16 + h * 8];
            half8 dvb = *(const half8*)&dTh[lxb][kt * 16 + h * 8];
            half8 sa = __builtin_elementwise_max(dva + pv[kt], hz);
            half8 sb = __builtin_elementwise_max(dvb + pv[kt], hz);
            aa = __builtin_amdgcn_mfma_f32_32x32x16_f16(sa, bf[kt], aa, 0, 0, 0);
            ab = __builtin_amdgcn_mfma_f32_32x32x16_f16(sb, bf[kt], ab, 0, 0, 0);
        }
        // D: col(kh)=wk*32+c32, row(ly)=(r&3)+8*(r>>2)+4h
        float pa[4] = {0.f, 0.f, 0.f, 0.f}, pb[4] = {0.f, 0.f, 0.f, 0.f};
        #pragma unroll
        for (int r = 0; r < 16; ++r) {
            float va = fmaxf(aa[r], 0.f);
            float vb = fmaxf(ab[r], 0.f);
            hy[r] += va + vb;
            pa[r & 3] += va;            // r is unroll-constant -> register index
            pb[r & 3] += vb;
        }
        float sa = (pa[0] + pa[1]) + (pa[2] + pa[3]);
        float sb = (pb[0] + pb[1]) + (pb[2] + pb[3]);
        sa += __shfl_xor(sa, 32);       // add other k-subgroup's 16 ly rows
        sb += __shfl_xor(sb, 32);
        if (h == 0) {                   // exclusive owner: plain LDS writes
            compW[lxa][wk * 32 + c32] = sa;
            compW[lxb][wk * 32 + c32] = sb;
        }
    }

    // ---- combine Hy across wl-waves (LDS atomics, once per block) ----
    #pragma unroll
    for (int r = 0; r < 16; ++r) {
        int ly = (r & 3) + 8 * (r >> 2) + 4 * h;
        atomicAdd(&protH[ly][wk * 32 + c32], hy[r]);
    }
    __syncthreads();

    // ---- block partials -> global, PLAIN coalesced stores ----
    {
        float* hxp = HxP + ((long)lyblk * (B_ * LX_) + b * LX_ + lxblk * 32) * 64;
        float* hyp = HyP + ((long)lxblk * (B_ * LY_) + b * LY_ + lyblk * 32) * 64;
        for (int u = t; u < 2048; u += 256) {
            int r = u >> 6, c = u & 63;
            hxp[u] = compW[r][c];
            hyp[u] = protH[r][c];
        }
    }
}

// ---------------- K3: sum partials -> (H*invN)@W_up + b_up -> gate -> out ---------
// grid (36, 8): x<4 drug (sum 32 slabs), else prot (sum 4 slabs). Full 128-c/block.
__global__ __launch_bounds__(256) void k3_gate(
    const float* __restrict__ HxP, const float* __restrict__ HyP,
    const float* __restrict__ wup, const float* __restrict__ bup,
    const float* __restrict__ x, const float* __restrict__ y,
    float* __restrict__ out)
{
    const int b = blockIdx.y;
    const int t = threadIdx.x;
    const float* part; const float* xin; float* outp; int L; float invN; int l0;
    int nq; long qstr;
    if (blockIdx.x < 4) {
        part = HxP; nq = 32; qstr = (long)B_ * LX_ * 64;
        xin = x; outp = out; L = LX_; invN = 1.f / 1024.f; l0 = blockIdx.x * 32;
    } else {
        part = HyP; nq = 4;  qstr = (long)B_ * LY_ * 64;
        xin = y; outp = out + (long)B_ * C_ * LX_; L = LY_; invN = 1.f / 128.f;
        l0 = (blockIdx.x - 4) * 32;
    }
    __shared__ float Ht[32][72];
    __shared__ float Wt[64][136];
    __shared__ float gg[32][133];

    const float* p0 = part + ((long)b * L + l0) * 64;
    for (int u = t; u < 2048; u += 256) {
        float a0 = 0.f, a1 = 0.f, a2 = 0.f, a3 = 0.f;
        #pragma unroll 4
        for (int q = 0; q < nq; q += 4) {
            a0 += p0[(long)q * qstr + u];
            a1 += p0[(long)(q + 1) * qstr + u];
            a2 += p0[(long)(q + 2) * qstr + u];
            a3 += p0[(long)(q + 3) * qstr + u];
        }
        Ht[u >> 6][u & 63] = (a0 + a1) + (a2 + a3);
    }
    #pragma unroll
    for (int i = 0; i < 8; ++i) {
        int idx = t + i * 256;                 // 2048 float4 = 64x128 floats
        int r = idx >> 5, c4 = (idx & 31) * 4;
        *(float4*)&Wt[r][c4] = *(const float4*)(wup + idx * 4);
    }
    __syncthreads();

    const int lrow = t >> 3, cg = (t & 7) * 4;  // c = cg + 32*jj + i
    float acc[4][4];
    #pragma unroll
    for (int jj = 0; jj < 4; ++jj)
        #pragma unroll
        for (int i = 0; i < 4; ++i) acc[jj][i] = 0.f;
    #pragma unroll 4
    for (int k = 0; k < 64; ++k) {
        float hv = Ht[lrow][k];
        #pragma unroll
        for (int jj = 0; jj < 4; ++jj) {
            float4 wv = *(const float4*)&Wt[k][cg + 32 * jj];
            acc[jj][0] = fmaf(hv, wv.x, acc[jj][0]);
            acc[jj][1] = fmaf(hv, wv.y, acc[jj][1]);
            acc[jj][2] = fmaf(hv, wv.z, acc[jj][2]);
            acc[jj][3] = fmaf(hv, wv.w, acc[jj][3]);
        }
    }
    #pragma unroll
    for (int jj = 0; jj < 4; ++jj)
        #pragma unroll
        for (int i = 0; i < 4; ++i) {
            int c = cg + 32 * jj + i;
            float v = fmaf(acc[jj][i], invN, bup[c]);
            float sg = 1.f / (1.f + expf(-v));
            gg[lrow][c] = sg * tanhf(v);
        }
    __syncthreads();
    for (int u = t; u < 4096; u += 256) {
        int c = u >> 5, li = u & 31;
        long idx = ((long)b * C_ + c) * L + l0 + li;
        outp[idx] = xin[idx] * (0.5f + gg[li][c]);
    }
}

extern "C" void kernel_launch(void* const* d_in, const int* in_sizes, int n_in,
                              void* d_out, int out_size, void* d_ws, size_t ws_size,
                              hipStream_t stream) {
    (void)in_sizes; (void)n_in; (void)out_size; (void)ws_size;
    const float* x     = (const float*)d_in[0];
    const float* y     = (const float*)d_in[1];
    const float* Wdrug = (const float*)d_in[2];
    const float* bdrug = (const float*)d_in[3];
    const float* Wprot = (const float*)d_in[4];
    const float* bprot = (const float*)d_in[5];
    const float* Wdown = (const float*)d_in[6];
    const float* bdown = (const float*)d_in[7];
    const float* Wup   = (const float*)d_in[8];
    const float* bup   = (const float*)d_in[9];
    float* out = (float*)d_out;
    char* ws = (char*)d_ws;

    _Float16* datt = (_Float16*)ws;                 // 131072 halves  (256 KB)
    _Float16* patt = (_Float16*)(ws + 262144);      // 1048576 halves (2 MB)
    _Float16* wdTh = (_Float16*)(ws + 2359296);     // 8192 halves    (16 KB)
    float*    HxP  = (float*)(ws + 2375680);        // 32*1024*64 f32 (8 MB)
    float*    HyP  = (float*)(ws + 10764288);       // 4*8192*64 f32  (8 MB)

    hipLaunchKernelGGL(k1_att, dim3(2304), dim3(128), 0, stream,
                       x, y, Wdrug, bdrug, Wprot, bprot, Wdown, datt, patt, wdTh);
    hipLaunchKernelGGL(k2_main, dim3(32, 32, 1), dim3(256), 0, stream,
                       datt, patt, wdTh, bdown, HxP, HyP);
    hipLaunchKernelGGL(k3_gate, dim3(36, 8), dim3(256), 0, stream,
                       HxP, HyP, Wup, bup, x, y, out);
}